// Round 4
// baseline (14304.274 us; speedup 1.0000x reference)
//
#include <hip/hip_runtime.h>
#include <hip/hip_bf16.h>
#include <math.h>

// ---------------------------------------------------------------------------
// MyRNN persistent kernel, round 4.
//   Phase A: xp = x@Wx^T + bx (unchanged; WG-private, barrier-free).
//   Phase B: 2048 steps, direct seqlock broadcast:
//     producer (wave 15): 32B bf16 data store -> vmcnt(0) -> seq[w]=t+1.
//     consumers: wave wv polls seq[wv*16 + lane] (one dense 64B line),
//       stages its 16 producers' records into LDS immediately on detect.
//     Two barriers/step. No tree, no go word.
//   Phase C: out = sigmoid(hT @ Wo^T + bo).
//
// ws layout (32-bit words):
//   [0,256)      seq[256] (dense; 16 cache lines; seq[w]=t+1 <=> h_{t+1} ready)
//   [1024,3072)  hb0: 256 records x 32B bf16 (h for even-step reads)
//   [3072,5120)  hb1: same, odd steps
//   [8192,...)   xp [256][2048][16] f32 (32 MiB)
// words [0,5120) memset to 0 every launch (h0=0, seq=0, deterministic replay).
// ---------------------------------------------------------------------------

#define T_STEPS  2048
#define INPUT_N  2048
#define HIDDEN_N 4096
#define NWG      256
#define NTHR     1024

typedef float f32x4 __attribute__((ext_vector_type(4)));
typedef unsigned int uint32;

__device__ __forceinline__ float wave_reduce(float v) {
#pragma unroll
  for (int off = 32; off > 0; off >>= 1) v += __shfl_xor(v, off, 64);
  return v;
}

__device__ __forceinline__ float bits_to_f(uint32 u) {
  union { uint32 u; float f; } c; c.u = u; return c.f;
}

__global__ __attribute__((amdgpu_flat_work_group_size(1024, 1024)))
__attribute__((amdgpu_waves_per_eu(4, 4))) void rnn_persistent(
    const float* __restrict__ x,
    const float* __restrict__ wh_w, const float* __restrict__ wh_b,
    const float* __restrict__ wx_w, const float* __restrict__ wx_b,
    const float* __restrict__ wo_w, const float* __restrict__ wo_b,
    float* __restrict__ out, float* __restrict__ ws) {
  const int w    = blockIdx.x;    // owns hidden rows [16w, 16w+16)
  const int tid  = threadIdx.x;
  const int lane = tid & 63;
  const int wv   = tid >> 6;      // wave 0..15

  int*    seq = (int*)ws;               // dense seq[256]
  uint32* hb0 = (uint32*)(ws + 1024);   // 256 records x 8 dwords
  uint32* hb1 = (uint32*)(ws + 3072);
  float*  xp  = ws + 8192;              // [w][t][16]

  __shared__ float s_h[HIDDEN_N];   // 16 KiB staged h (f32)
  __shared__ float s_hnew[16];

  // ------------------ Phase A: xp (barrier-free, reduce-free) --------------
  {
    const int tq = lane >> 4;        // 0..3
    const int r  = lane & 15;        // row within WG slice
    const float* wrow = wx_w + (size_t)(w * 16 + r) * INPUT_N;
    const float  bA   = wx_b[w * 16 + r];
    for (int g = wv; g < 64; g += 16) {       // 4 groups per wave
      const int t0 = g * 32 + tq;             // t = t0 + 4j, j<8
      f32x4 acc[8];
      const float* xr[8];
#pragma unroll
      for (int j = 0; j < 8; ++j) {
        acc[j] = (f32x4){0.f, 0.f, 0.f, 0.f};
        xr[j]  = x + (size_t)(t0 + 4 * j) * INPUT_N;
      }
      for (int k = 0; k < 512; ++k) {         // 16B granules over K=2048
        f32x4 wq = *(const f32x4*)(wrow + (size_t)k * 4);
#pragma unroll
        for (int j = 0; j < 8; ++j)
          acc[j] += (*(const f32x4*)(xr[j] + (size_t)k * 4)) * wq;
      }
#pragma unroll
      for (int j = 0; j < 8; ++j) {
        float s = acc[j].x + acc[j].y + acc[j].z + acc[j].w + bA;
        xp[((size_t)w * T_STEPS + (t0 + 4 * j)) * 16 + r] = s;
      }
    }
  }
  __syncthreads();   // xp slice complete (WG-private, same CU)

  // ------------------ Phase B: the scan ------------------------------------
  const float* whrow = wh_w + (size_t)(w * 16 + wv) * HIDDEN_N + lane * 4;
  f32x4 W[16];
#pragma unroll
  for (int i = 0; i < 16; ++i) W[i] = *(const f32x4*)(whrow + i * 256);
  const float bB = wh_b[w * 16 + wv];
  const int   myseq = wv * 16 + (lane & 15);   // seq word this lane monitors
  const int   mydw  = wv * 128 + lane;         // dword this lane stages (x2)

  for (int t = 0; t < T_STEPS; ++t) {
    // prefetch xp[t][wv] (uniform per wave, WG-private, latency hidden)
    const float xpv = xp[((size_t)w * T_STEPS + t) * 16 + wv];

    // 1) per-wave: wait for my 16 producers, then stage their records
    if (t > 0) {
      for (;;) {
        int v = __hip_atomic_load(&seq[myseq], __ATOMIC_RELAXED,
                                  __HIP_MEMORY_SCOPE_AGENT);
        if (__all(v >= t)) break;
        __builtin_amdgcn_s_sleep(2);
      }
    }
    {
      const uint32* src = (t & 1) ? hb1 : hb0;
      uint32 u0 = __hip_atomic_load(src + mydw, __ATOMIC_RELAXED,
                                    __HIP_MEMORY_SCOPE_AGENT);
      uint32 u1 = __hip_atomic_load(src + mydw + 64, __ATOMIC_RELAXED,
                                    __HIP_MEMORY_SCOPE_AGENT);
      float2 p0, p1;
      p0.x = bits_to_f(u0 << 16);  p0.y = bits_to_f(u0 & 0xffff0000u);
      p1.x = bits_to_f(u1 << 16);  p1.y = bits_to_f(u1 & 0xffff0000u);
      *(float2*)&s_h[2 * mydw]        = p0;
      *(float2*)&s_h[2 * (mydw + 64)] = p1;
    }
    __syncthreads();

    // 2) full-row dot from LDS against resident W
    f32x4 a0 = {0.f, 0.f, 0.f, 0.f}, a1 = {0.f, 0.f, 0.f, 0.f};
#pragma unroll
    for (int i = 0; i < 16; i += 2) {
      a0 += (*(const f32x4*)&s_h[lane * 4 + i * 256]) * W[i];
      a1 += (*(const f32x4*)&s_h[lane * 4 + (i + 1) * 256]) * W[i + 1];
    }
    float d = wave_reduce(a0.x + a0.y + a0.z + a0.w +
                          a1.x + a1.y + a1.z + a1.w);
    if (lane == 0) s_hnew[wv] = tanhf(d + bB + xpv);
    __syncthreads();

    // 3) wave 15: publish record + seq (everyone else loops to poll)
    if (wv == 15) {
      uint32* dst = ((t & 1) ? hb0 : hb1) + w * 8;   // h_{t+1} buffer
      if (lane < 8) {
        __hip_bfloat16 blo = __float2bfloat16(s_hnew[2 * lane]);
        __hip_bfloat16 bhi = __float2bfloat16(s_hnew[2 * lane + 1]);
        uint32 v = (uint32)(*(unsigned short*)&blo) |
                   ((uint32)(*(unsigned short*)&bhi) << 16);
        __hip_atomic_store(dst + lane, v, __ATOMIC_RELAXED,
                           __HIP_MEMORY_SCOPE_AGENT);
      }
      asm volatile("s_waitcnt vmcnt(0)" ::: "memory");  // data at L3
      if (lane == 0)
        __hip_atomic_store(&seq[w], t + 1, __ATOMIC_RELAXED,
                           __HIP_MEMORY_SCOPE_AGENT);
    }
  }

  // ------------------ Phase C: output --------------------------------------
  {
    for (;;) {
      int v = __hip_atomic_load(&seq[myseq], __ATOMIC_RELAXED,
                                __HIP_MEMORY_SCOPE_AGENT);
      if (__all(v >= T_STEPS)) break;
      __builtin_amdgcn_s_sleep(2);
    }
    const uint32* src = hb0;   // h_2048 lives in hb[2048&1] = hb0
    uint32 u0 = __hip_atomic_load(src + mydw, __ATOMIC_RELAXED,
                                  __HIP_MEMORY_SCOPE_AGENT);
    uint32 u1 = __hip_atomic_load(src + mydw + 64, __ATOMIC_RELAXED,
                                  __HIP_MEMORY_SCOPE_AGENT);
    float2 p0, p1;
    p0.x = bits_to_f(u0 << 16);  p0.y = bits_to_f(u0 & 0xffff0000u);
    p1.x = bits_to_f(u1 << 16);  p1.y = bits_to_f(u1 & 0xffff0000u);
    *(float2*)&s_h[2 * mydw]        = p0;
    *(float2*)&s_h[2 * (mydw + 64)] = p1;
  }
  __syncthreads();
  if (wv < 8) {
    const int o = w * 8 + wv;
    const float* worow = wo_w + (size_t)o * HIDDEN_N + lane * 4;
    f32x4 acc = {0.f, 0.f, 0.f, 0.f};
#pragma unroll
    for (int k = 0; k < 16; ++k)
      acc += (*(const f32x4*)(worow + k * 256)) *
             (*(const f32x4*)&s_h[lane * 4 + k * 256]);
    float s = wave_reduce(acc.x + acc.y + acc.z + acc.w);
    if (lane == 0) {
      float z = s + wo_b[o];
      out[o] = 1.f / (1.f + expf(-z));
    }
  }
}

extern "C" void kernel_launch(void* const* d_in, const int* in_sizes, int n_in,
                              void* d_out, int out_size, void* d_ws,
                              size_t ws_size, hipStream_t stream) {
  const float* x    = (const float*)d_in[0];
  const float* wh_w = (const float*)d_in[1];
  const float* wh_b = (const float*)d_in[2];
  const float* wx_w = (const float*)d_in[3];
  const float* wx_b = (const float*)d_in[4];
  const float* wo_w = (const float*)d_in[5];
  const float* wo_b = (const float*)d_in[6];
  float* out = (float*)d_out;
  float* ws  = (float*)d_ws;

  // seq + h double-buffers zeroed every call (h0 = 0, deterministic replay)
  hipMemsetAsync(d_ws, 0, 5120 * 4, stream);

  hipLaunchKernelGGL(rnn_persistent, dim3(NWG), dim3(NTHR), 0, stream,
                     x, wh_w, wh_b, wx_w, wx_b, wo_w, wo_b, out, ws);
}